// Round 2
// baseline (401.706 us; speedup 1.0000x reference)
//
#include <hip/hip_runtime.h>
#include <stdint.h>

#define IC   4096
#define BLK  256
#define VPT  4          // float4 chunks per thread (16 elems/thread)
#define EPT  (VPT * 4)

// ---- fp64 block reductions (4 waves fixed), result broadcast ----
__device__ __forceinline__ void block_sum2_d(double& a, double& b, double* sm) {
    #pragma unroll
    for (int off = 32; off; off >>= 1) {
        a += __shfl_xor(a, off);
        b += __shfl_xor(b, off);
    }
    const int wid = threadIdx.x >> 6;
    if ((threadIdx.x & 63) == 0) { sm[wid] = a; sm[4 + wid] = b; }
    __syncthreads();
    a = sm[0] + sm[1] + sm[2] + sm[3];
    b = sm[4] + sm[5] + sm[6] + sm[7];
    __syncthreads();
}

__device__ __forceinline__ double block_sum1_d(double a, double* sm) {
    #pragma unroll
    for (int off = 32; off; off >>= 1) a += __shfl_xor(a, off);
    const int wid = threadIdx.x >> 6;
    if ((threadIdx.x & 63) == 0) sm[wid] = a;
    __syncthreads();
    a = sm[0] + sm[1] + sm[2] + sm[3];
    __syncthreads();
    return a;
}

__device__ __forceinline__ double dsign(double v) {
    return (v > 0.0) ? 1.0 : ((v < 0.0) ? -1.0 : 0.0);
}

__global__ __launch_bounds__(BLK) void binarize_kernel(
    const float* __restrict__ x,
    const uint8_t* __restrict__ mask,
    float* __restrict__ out)
{
    __shared__ double sm[8];
    const int row = blockIdx.x;
    const int tid = threadIdx.x;

    // ---- mask dtype detection (grid-uniform result) ----
    // int32 0/1 mask: every 32-bit word <= 1.  1-byte bool mask: 4 packed
    // random 0/1 bytes -> some word of the first 256 is > 1 w.p. ~1.
    double bad = (((const uint32_t*)mask)[tid] > 1u) ? 1.0 : 0.0;
    const bool mask_is_i32 = (block_sum1_d(bad, sm) == 0.0);

    const float* xr   = x + (size_t)row * IC;
    float*       orow = out + (size_t)row * IC;

    float xf[EPT];     // raw fp32 x (exact when widened to fp64)
    float mv[EPT];     // mask as 0.0f / 1.0f

    #pragma unroll
    for (int i = 0; i < VPT; ++i) {
        float4 v = ((const float4*)xr)[tid + i * BLK];
        xf[i*4+0] = v.x; xf[i*4+1] = v.y; xf[i*4+2] = v.z; xf[i*4+3] = v.w;
    }

    if (mask_is_i32) {
        const int4* mr = (const int4*)mask + (size_t)row * (IC / 4);
        #pragma unroll
        for (int i = 0; i < VPT; ++i) {
            int4 m4 = mr[tid + i * BLK];
            mv[i*4+0] = m4.x ? 1.f : 0.f;
            mv[i*4+1] = m4.y ? 1.f : 0.f;
            mv[i*4+2] = m4.z ? 1.f : 0.f;
            mv[i*4+3] = m4.w ? 1.f : 0.f;
        }
    } else {
        const uint32_t* mr = (const uint32_t*)(mask + (size_t)row * IC);
        #pragma unroll
        for (int i = 0; i < VPT; ++i) {
            uint32_t w = mr[tid + i * BLK];
            mv[i*4+0] = (w & 0x000000ffu) ? 1.f : 0.f;
            mv[i*4+1] = (w & 0x0000ff00u) ? 1.f : 0.f;
            mv[i*4+2] = (w & 0x00ff0000u) ? 1.f : 0.f;
            mv[i*4+3] = (w & 0xff000000u) ? 1.f : 0.f;
        }
    }

    // ---- pass A: masked sum + count -> mean1 (all fp64) ----
    double s = 0.0, c = 0.0;
    #pragma unroll
    for (int j = 0; j < EPT; ++j) {
        const double m = (double)mv[j];
        s += (double)xf[j] * m;
        c += m;
    }
    block_sum2_d(s, c, sm);

    const bool   has   = (c > 0.0);
    const double inv   = 1.0 / fmax(c, 1.0);
    const double mean1 = has ? s * inv : 0.0;

    // ---- pass B: scale1 = masked mean |x - mean1| ----
    double sa = 0.0;
    #pragma unroll
    for (int j = 0; j < EPT; ++j)
        sa += fabs((double)xf[j] - mean1) * (double)mv[j];
    sa = block_sum1_d(sa, sm);
    const double scale1 = has ? sa * inv : 0.0;

    // ---- pass C: r2 = (x - b1)*m, mean2 ----
    double s2 = 0.0;
    #pragma unroll
    for (int j = 0; j < EPT; ++j) {
        const double xv = (double)xf[j], m = (double)mv[j];
        const double b1 = dsign(xv - mean1) * scale1 + mean1;
        s2 += (xv - b1) * m;
    }
    s2 = block_sum1_d(s2, sm);
    const double mean2 = has ? s2 * inv : 0.0;

    // ---- pass D: scale2 = masked mean |r2 - mean2| ----
    double sa2 = 0.0;
    #pragma unroll
    for (int j = 0; j < EPT; ++j) {
        const double xv = (double)xf[j], m = (double)mv[j];
        const double b1 = dsign(xv - mean1) * scale1 + mean1;
        const double r2 = (xv - b1) * m;
        sa2 += fabs(r2 - mean2) * m;
    }
    sa2 = block_sum1_d(sa2, sm);
    const double scale2 = has ? sa2 * inv : 0.0;

    // ---- epilogue: out = (b1 + b2) * m ----
    #pragma unroll
    for (int i = 0; i < VPT; ++i) {
        float4 o;
        float* op = &o.x;
        #pragma unroll
        for (int k = 0; k < 4; ++k) {
            const int j = i * 4 + k;
            const double xv = (double)xf[j], m = (double)mv[j];
            const double b1  = dsign(xv - mean1) * scale1 + mean1;
            const double r2  = (xv - b1) * m;
            const double ce2 = (r2 - mean2) * m;
            const double b2  = dsign(ce2) * scale2 + mean2;
            op[k] = (float)((b1 + b2) * m);
        }
        ((float4*)orow)[tid + i * BLK] = o;
    }
}

extern "C" void kernel_launch(void* const* d_in, const int* in_sizes, int n_in,
                              void* d_out, int out_size, void* d_ws, size_t ws_size,
                              hipStream_t stream) {
    const float*   x    = (const float*)d_in[0];
    const uint8_t* mask = (const uint8_t*)d_in[1];
    float*         out  = (float*)d_out;

    const int rows = in_sizes[0] / IC;   // 11008
    binarize_kernel<<<rows, BLK, 0, stream>>>(x, mask, out);
}